// Round 11
// baseline (449.352 us; speedup 1.0000x reference)
//
#include <hip/hip_runtime.h>
#include <hip/hip_cooperative_groups.h>
#include <math.h>

namespace cg = cooperative_groups;

#define N_NODES 50000
#define N_EDGES 800000
#define N_GRAPHS 16
#define NODE_F 128
#define HID 64
#define OUT_F 128
#define HEADS 3
#define NEG 0.2f
#define FEAT (HEADS*HID)  // 192

typedef float f32x4 __attribute__((ext_vector_type(4)));
typedef float f32x2 __attribute__((ext_vector_type(2)));
typedef short bf16x8 __attribute__((ext_vector_type(8)));

#if defined(__has_builtin)
#if __has_builtin(__builtin_amdgcn_cvt_pk_f32_fp8) && __has_builtin(__builtin_amdgcn_cvt_pk_fp8_f32)
#define USE_FP8 1
#endif
#endif
#ifndef USE_FP8
#define USE_FP8 0
#endif

#if USE_FP8
#define FB 1  // bytes per stored feat element
#else
#define FB 2
#endif
// feat layout: PACKED head-major (R10). element (hh,dd) at byte hh*HID*FB + dd*FB.
#define ROWB (FEAT * FB)  // 192 fp8 / 384 bf16

// ---- R3: atomic-free CSR build via bucket counting sort (R0-R2: global atomics ~13 G/s wall).
// ---- R4: chain compression. R5 (REVERTED) mega-fusion. R6 (NULL) gather unroll.
// ---- R7: k01 LDS epilogue (-5us). R8/R9 (REVERTED). R10 (NULL) packed rows ->
//      k4 gather is latency-floor-bound, not traffic-bound.
// ---- R11: launch consolidation. kh2a+kh3+kh4 -> ksort_coop (2 grid.sync);
//      k5a+k6 -> k56_coop (1 grid.sync). 8 -> 5 launches; bodies unchanged.
#define NBKT ((N_NODES + 63) / 64)   // 782
#define H1B 400                      // hist/scatter blocks
#define EPB (N_EDGES / H1B)          // 2000 edges per block (exact)
#define LROW2 208                    // LDS feat row stride (13x16B)

__device__ __forceinline__ ushort f2bf(float x) {
  union { float f; unsigned u; } v; v.f = x;
  unsigned r = v.u + 0x7fff + ((v.u >> 16) & 1);  // round-to-nearest-even
  return (ushort)(r >> 16);
}
__device__ __forceinline__ float bf2f(ushort x) {
  union { unsigned u; float f; } v; v.u = ((unsigned)x) << 16;
  return v.f;
}

// store one feat element: head hh, dim dd (bf16 fallback path only)
__device__ __forceinline__ void feat_store(unsigned char* base, int n, int hh, int dd, float v) {
  size_t off = (size_t)n * ROWB + (hh * HID + dd) * FB;
#if USE_FP8
  base[off] = (unsigned char)(__builtin_amdgcn_cvt_pk_fp8_f32(v, 0.f, 0, false) & 0xff);
#else
  *(ushort*)(base + off) = f2bf(v);
#endif
}

// ---------------- KPREP: [0..23] fc_w -> fcb bf16 fragment repack | [24..25] zero residues ----------------
#define ZERO_INTS (N_GRAPHS * HID + N_GRAPHS)  // pooled_res, gcnt_res
#define ZERO_U4 (ZERO_INTS / 4)                // 260
#define ZB ((ZERO_U4 + 255) / 256)             // 2
__global__ void kprep(const float* __restrict__ fc_w, ushort* __restrict__ fcb,
                      uint4* __restrict__ zbase) {
  if (blockIdx.x >= 24) {
    int i = (blockIdx.x - 24) * 256 + threadIdx.x;
    if (i < ZERO_U4) zbase[i] = make_uint4(0, 0, 0, 0);
    return;
  }
  int i = blockIdx.x * 256 + threadIdx.x;  // [0, 6144)
  int col = i >> 5;             // [0,192)
  int kb = (i & 31) * 4;        // k base, multiple of 4
  float4 v = *(const float4*)(fc_w + (size_t)col * NODE_F + kb);
  int t = col >> 4, m = col & 15;
  int kk = kb >> 5, kq = (kb >> 3) & 3, j = kb & 7;
  size_t idx0 = ((((size_t)t * 4 + kk) * 4 + kq) * 16 + m) * 8 + j;
  ushort4 o; o.x = f2bf(v.x); o.y = f2bf(v.y); o.z = f2bf(v.z); o.w = f2bf(v.w);
  *(ushort4*)(fcb + idx0) = o;  // 8-B aligned (j in {0,4})
}

// ---------------- K01 fused: [blocks < H1B] coarse hist (LDS atomics) | [rest] MFMA GEMM ----------------
#define GB0 ((N_NODES + 63) / 64)  // 782
__global__ __launch_bounds__(256) void k01_fused(
    const float* __restrict__ h, const ushort* __restrict__ fcb,
    const float* __restrict__ attn_l, const float* __restrict__ attn_r,
    const int* __restrict__ dst,
    unsigned char* __restrict__ feat, float* __restrict__ el, float* __restrict__ er,
    int* __restrict__ cnt_g)
{
  __shared__ ushort A[64][136];   // 17408 B; hist: int cnt[NBKT]; epilogue: 64 x LROW2 feat rows
  const int tid = threadIdx.x;

  if (blockIdx.x < H1B) {
    int* cnt = (int*)&A[0][0];
    const int blk = blockIdx.x;
    for (int i = tid; i < NBKT; i += 256) cnt[i] = 0;
    __syncthreads();
    const int e0 = blk * EPB;
    for (int i = tid; i < EPB; i += 256)
      atomicAdd(&cnt[dst[e0 + i] >> 6], 1);
    __syncthreads();
    for (int i = tid; i < NBKT; i += 256) cnt_g[(size_t)blk * NBKT + i] = cnt[i];
    return;
  }

  const int n0 = (blockIdx.x - H1B) * 64;
  for (int i = tid; i < 64 * 32; i += 256) {
    int r = i >> 5, c4 = i & 31;
    if (n0 + r < N_NODES) {
      float4 v = *(const float4*)(h + (size_t)(n0 + r) * NODE_F + c4 * 4);
      unsigned lo = f2bf(v.x) | ((unsigned)f2bf(v.y) << 16);
      unsigned hi = f2bf(v.z) | ((unsigned)f2bf(v.w) << 16);
      *(uint2*)&A[r][c4 * 4] = make_uint2(lo, hi);
    }
  }
  __syncthreads();  // staging visible

  const int lane = tid & 63, wv = tid >> 6;
  const int m = lane & 15, kq = lane >> 4;

  f32x4 acc[12];
#pragma unroll
  for (int t = 0; t < 12; t++) acc[t] = (f32x4){0.f, 0.f, 0.f, 0.f};

#pragma unroll
  for (int kk = 0; kk < 4; kk++) {
    bf16x8 af = *(const bf16x8*)&A[wv * 16 + m][kk * 32 + kq * 8];
#pragma unroll
    for (int t = 0; t < 12; t++) {
      const bf16x8 bf = *(const bf16x8*)(fcb + ((((size_t)t * 4 + kk) * 4 + kq) * 16 + m) * 8);
      acc[t] = __builtin_amdgcn_mfma_f32_16x16x32_bf16(af, bf, acc[t], 0, 0, 0);
    }
  }

  const int rbase = n0 + wv * 16 + kq * 4;

#if USE_FP8
  // ---- LDS-assemble packed fp8 rows (A reused), then coalesced write-out ----
  __syncthreads();  // all waves done reading A
  unsigned char* lf = (unsigned char*)&A[0][0];  // 64 rows x LROW2 bytes
  const int rloc = wv * 16 + kq * 4;
#pragma unroll
  for (int t = 0; t < 12; t++) {
    const int hh = t >> 2;
    const int dd = (t & 3) * 16 + m;
    const int boff = hh * HID + dd;  // packed head-major
#pragma unroll
    for (int reg = 0; reg < 4; reg++) {
      unsigned char q = (unsigned char)(__builtin_amdgcn_cvt_pk_fp8_f32(acc[t][reg], 0.f, 0, false) & 0xff);
      lf[(rloc + reg) * LROW2 + boff] = q;
    }
  }
#else
#pragma unroll
  for (int t = 0; t < 12; t++) {
    const int hh = t >> 2;
    const int dd = (t & 3) * 16 + m;
#pragma unroll
    for (int reg = 0; reg < 4; reg++) {
      int n = rbase + reg;
      if (n < N_NODES) feat_store(feat, n, hh, dd, acc[t][reg]);
    }
  }
#endif

  // el/er epilogue (registers + shfl only) — overlaps the LDS scatter latency
#pragma unroll
  for (int hh = 0; hh < HEADS; hh++) {
    float elv[4] = {0.f, 0.f, 0.f, 0.f};
    float erv[4] = {0.f, 0.f, 0.f, 0.f};
#pragma unroll
    for (int tt = 0; tt < 4; tt++) {
      int t = hh * 4 + tt;
      float al = attn_l[hh * HID + tt * 16 + m];
      float ar = attn_r[hh * HID + tt * 16 + m];
#pragma unroll
      for (int reg = 0; reg < 4; reg++) {
        elv[reg] = fmaf(acc[t][reg], al, elv[reg]);
        erv[reg] = fmaf(acc[t][reg], ar, erv[reg]);
      }
    }
#pragma unroll
    for (int reg = 0; reg < 4; reg++) {
#pragma unroll
      for (int off = 1; off < 16; off <<= 1) {
        elv[reg] += __shfl_xor(elv[reg], off, 64);
        erv[reg] += __shfl_xor(erv[reg], off, 64);
      }
      int n = rbase + reg;
      if (m == 0 && n < N_NODES) {
        el[(size_t)n * 4 + hh] = elv[reg];
        er[(size_t)n * 4 + hh] = erv[reg];
      }
    }
  }

#if USE_FP8
  __syncthreads();  // LDS rows complete
  // coalesced write-out: 64 rows x 192 B = 768 uint4; 3 per thread
  for (int i = tid; i < 64 * (ROWB / 16); i += 256) {
    int r = i / (ROWB / 16), c = (i % (ROWB / 16)) * 16;
    int n = n0 + r;
    if (n < N_NODES)
      *(uint4*)(feat + (size_t)n * ROWB + c) = *(const uint4*)(lf + r * LROW2 + c);
  }
#endif
}

// ---------------- KSORT (cooperative): kh2a | sync | kh3 | sync | kh4 ----------------
#define H2A_K 7  // ceil(400/64)
__global__ __launch_bounds__(256) void ksort_coop(
    const int* __restrict__ src, const int* __restrict__ dst,
    const int* __restrict__ cnt_g, int* __restrict__ base_bm, int* __restrict__ btot,
    int2* __restrict__ pairs, int* __restrict__ src_s, int* __restrict__ offs)
{
  cg::grid_group grid = cg::this_grid();
  __shared__ int cur[NBKT];
  __shared__ int wsum[4];
  __shared__ int nodecnt[64];
  __shared__ int cur2[64];
  __shared__ int red_[4];
  __shared__ int lo_s, hi_s;
  const int tid = threadIdx.x;
  const int lane = tid & 63, wv = tid >> 6;

  // ---- phase 1: per-bucket exclusive scan over hist blocks (wave 0 only; block = bucket) ----
  if (tid < 64) {
    const int b = blockIdx.x;
    int v[H2A_K];
    int lt = 0;
#pragma unroll
    for (int j = 0; j < H2A_K; j++) {
      int g = lane * H2A_K + j;
      v[j] = (g < H1B) ? cnt_g[(size_t)g * NBKT + b] : 0;
      lt += v[j];
    }
    int s = lt;
#pragma unroll
    for (int off = 1; off < 64; off <<= 1) {
      int t = __shfl_up(s, off, 64);
      if (lane >= off) s += t;
    }
    int excl = s - lt;
#pragma unroll
    for (int j = 0; j < H2A_K; j++) {
      int g = lane * H2A_K + j;
      if (g < H1B) base_bm[(size_t)b * H1B + g] = excl;
      excl += v[j];
    }
    if (lane == 63) btot[b] = s;
  }
  grid.sync();

  // ---- phase 2: scatter (src,dst) into bucket-sorted order (blocks 0..H1B-1) ----
  if (blockIdx.x < H1B) {
    const int blk = blockIdx.x;
    int v[4]; int lt = 0;
#pragma unroll
    for (int j = 0; j < 4; j++) {
      int g = tid * 4 + j;
      v[j] = (g < NBKT) ? btot[g] : 0;
      lt += v[j];
    }
    int s = lt;
#pragma unroll
    for (int off = 1; off < 64; off <<= 1) {
      int t = __shfl_up(s, off, 64);
      if (lane >= off) s += t;
    }
    if (lane == 63) wsum[wv] = s;
    __syncthreads();
    int woff = 0;
#pragma unroll
    for (int w = 0; w < 4; w++) woff += (w < wv) ? wsum[w] : 0;
    int excl = s - lt + woff;
#pragma unroll
    for (int j = 0; j < 4; j++) {
      int g = tid * 4 + j;
      if (g < NBKT) cur[g] = excl + base_bm[(size_t)g * H1B + blk];
      excl += v[j];
    }
    __syncthreads();
    const int e0 = blk * EPB;
    for (int i = tid; i < EPB; i += 256) {
      int e = e0 + i;
      int d = dst[e], sv = src[e];
      int slot = atomicAdd(&cur[d >> 6], 1);  // returning LDS atomic (fast pipe)
      pairs[slot] = make_int2(sv, d);
    }
  }
  grid.sync();

  // ---- phase 3: per-bucket node sort -> exact CSR offs + node-sorted src ----
  {
    const int b = blockIdx.x;
    int partial = 0;
    for (int i = tid; i < b; i += 256) partial += btot[i];
#pragma unroll
    for (int off = 32; off; off >>= 1) partial += __shfl_xor(partial, off, 64);
    if (lane == 0) red_[wv] = partial;
    if (tid < 64) nodecnt[tid] = 0;
    __syncthreads();
    if (tid == 0) {
      int l = red_[0] + red_[1] + red_[2] + red_[3];
      lo_s = l; hi_s = l + btot[b];
    }
    __syncthreads();
    const int lo = lo_s, hi = hi_s;
    for (int i = lo + tid; i < hi; i += 256)
      atomicAdd(&nodecnt[pairs[i].y & 63], 1);
    __syncthreads();
    if (tid < 64) {
      int v = nodecnt[tid];
      int s = v;
#pragma unroll
      for (int off = 1; off < 64; off <<= 1) {
        int t = __shfl_up(s, off, 64);
        if (tid >= off) s += t;
      }
      int excl = s - v;
      cur2[tid] = lo + excl;
      int n = b * 64 + tid;
      if (n < N_NODES) offs[n] = lo + excl;
      if (b == NBKT - 1 && tid == 0) offs[N_NODES] = N_EDGES;
    }
    __syncthreads();
    for (int i = lo + tid; i < hi; i += 256) {
      int2 pr = pairs[i];
      int slot = atomicAdd(&cur2[pr.y & 63], 1);
      src_s[slot] = pr.x;
    }
  }
}

// ---------------- K4: wave per node; weights inline; 3-narrow-load packed gather ----------------
__global__ __launch_bounds__(256) void k4_agg(
    const int* __restrict__ offs, const int* __restrict__ src_s,
    const float* __restrict__ el4, const float* __restrict__ er4,
    const unsigned char* __restrict__ feat, const float* __restrict__ bias,
    float* __restrict__ h_d)
{
  __shared__ float4 rec[4][64];  // per-wave staging, 4 KB/block
  const int wv = threadIdx.x >> 6, lane = threadIdx.x & 63;
  const int n = blockIdx.x * 4 + wv;  // grid exact: N/4
  const int lo = offs[n], hi = offs[n + 1];
  const int half = lane >> 5;
  const int d = lane & 31;
  const char* fb = (const char*)feat;
  const float4 ern = ((const float4*)er4)[n];

  float a0x = 0.f, a0y = 0.f, a1x = 0.f, a1y = 0.f, a2x = 0.f, a2y = 0.f;
  float s0 = 0.f, s1 = 0.f, s2 = 0.f;

  for (int base = lo; base < hi; base += 64) {
    const int cnt = min(64, hi - base);
    if (lane < cnt) {
      int sidx = src_s[base + lane];
      float4 elv = ((const float4*)el4)[sidx];
      float e0 = elv.x + ern.x; e0 = e0 > 0.f ? e0 : NEG * e0;
      float e1 = elv.y + ern.y; e1 = e1 > 0.f ? e1 : NEG * e1;
      float e2 = elv.z + ern.z; e2 = e2 > 0.f ? e2 : NEG * e2;
      float4 c;
      c.x = __expf(e0); c.y = __expf(e1); c.z = __expf(e2);
      c.w = __int_as_float(sidx * ROWB);  // byte offset of packed feat row
      rec[wv][lane] = c;
      s0 += c.x; s1 += c.y; s2 += c.z;  // each edge counted once (by its staging lane)
    }
#define K4_BODY(J) do { \
      float4 c = rec[wv][J]; \
      f32x2 f0, f1, f2; \
      if (USE_FP8) { \
        const char* rp = fb + __float_as_int(c.w) + 2 * d; \
        ushort u0 = *(const ushort*)(rp); \
        ushort u1 = *(const ushort*)(rp + HID); \
        ushort u2 = *(const ushort*)(rp + 2 * HID); \
        f0 = __builtin_amdgcn_cvt_pk_f32_fp8(u0, false); \
        f1 = __builtin_amdgcn_cvt_pk_f32_fp8(u1, false); \
        f2 = __builtin_amdgcn_cvt_pk_f32_fp8(u2, false); \
      } else { \
        const char* rp = fb + __float_as_int(c.w) + 4 * d; \
        unsigned q0 = *(const unsigned*)(rp); \
        unsigned q1 = *(const unsigned*)(rp + 2 * HID); \
        unsigned q2 = *(const unsigned*)(rp + 4 * HID); \
        f0.x = bf2f((ushort)(q0 & 0xffff)); f0.y = bf2f((ushort)(q0 >> 16)); \
        f1.x = bf2f((ushort)(q1 & 0xffff)); f1.y = bf2f((ushort)(q1 >> 16)); \
        f2.x = bf2f((ushort)(q2 & 0xffff)); f2.y = bf2f((ushort)(q2 >> 16)); \
      } \
      a0x = fmaf(c.x, f0.x, a0x); a0y = fmaf(c.x, f0.y, a0y); \
      a1x = fmaf(c.y, f1.x, a1x); a1y = fmaf(c.y, f1.y, a1y); \
      a2x = fmaf(c.z, f2.x, a2x); a2y = fmaf(c.z, f2.y, a2y); \
    } while (0)
    int j = half;
    for (; j + 2 < cnt; j += 4) { K4_BODY(j); K4_BODY(j + 2); }
    if (j < cnt) K4_BODY(j);
#undef K4_BODY
  }
  // combine the two half-wave edge partitions (same dims, disjoint edges)
  a0x += __shfl_xor(a0x, 32, 64); a0y += __shfl_xor(a0y, 32, 64);
  a1x += __shfl_xor(a1x, 32, 64); a1y += __shfl_xor(a1y, 32, 64);
  a2x += __shfl_xor(a2x, 32, 64); a2y += __shfl_xor(a2y, 32, 64);
#pragma unroll
  for (int off = 32; off; off >>= 1) {
    s0 += __shfl_xor(s0, off, 64);
    s1 += __shfl_xor(s1, off, 64);
    s2 += __shfl_xor(s2, off, 64);
  }
  const float i0 = s0 > 0.f ? 1.f / s0 : 0.f;
  const float i1 = s1 > 0.f ? 1.f / s1 : 0.f;
  const float i2 = s2 > 0.f ? 1.f / s2 : 0.f;
  if (half == 0) {
    float2 b0 = *(const float2*)(bias + 2 * d);
    float2 b1 = *(const float2*)(bias + HID + 2 * d);
    float2 b2 = *(const float2*)(bias + 2 * HID + 2 * d);
    float2 o;
    o.x = (fmaf(a0x, i0, b0.x) + fmaf(a1x, i1, b1.x) + fmaf(a2x, i2, b2.x)) * (1.f / 3.f);
    o.y = (fmaf(a0y, i0, b0.y) + fmaf(a1y, i1, b1.y) + fmaf(a2y, i2, b2.y)) * (1.f / 3.f);
    *(float2*)(h_d + (size_t)n * HID + 2 * d) = o;
  }
}

// ---------------- K56 (cooperative): k5a partials | sync | k6 final ----------------
#define K5_NPB 128
#define K5_NB ((N_NODES + K5_NPB - 1) / K5_NPB)  // 391
#define NSEG (K5_NB * 2)                         // 782
__global__ __launch_bounds__(256) void k56_coop(
    const int* __restrict__ graph_id, const float* __restrict__ h_d,
    float* __restrict__ pooled_res, int* __restrict__ gcnt_res,
    float* __restrict__ part, int* __restrict__ pg, int* __restrict__ pc,
    const float* __restrict__ z,
    const float* __restrict__ lin1_w, const float* __restrict__ lin1_b,
    const float* __restrict__ lin2_w, const float* __restrict__ lin2_b,
    float* __restrict__ out)
{
  cg::grid_group grid = cg::this_grid();
  const int tid = threadIdx.x;
  const int wv = tid >> 6, lane = tid & 63;
  __shared__ float ls[2][4][64];
  __shared__ int lc[2][4];
  __shared__ int spg[NSEG], spc[NSEG];
  __shared__ float red[4][HID];
  __shared__ int rc[4];
  __shared__ float cat[2 * HID];

  // ---- phase 1: k5a block partials ----
  {
    const int b = blockIdx.x;
    const int n0 = b * K5_NPB;
    const int n1 = min(n0 + K5_NPB, N_NODES);
    const int g_lo = graph_id[n0], g_hi = graph_id[n1 - 1];

    if (g_hi > g_lo + 1) {
      // rare path: per-wave atomic flush
      float acc = 0.f; int cur_g = -1; int cnt = 0;
      for (int i = n0 + wv; i < n1; i += 4) {
        int g = graph_id[i];
        if (g != cur_g) {
          if (cur_g >= 0) {
            atomicAdd(&pooled_res[cur_g * HID + lane], acc);
            if (lane == 0) atomicAdd(&gcnt_res[cur_g], cnt);
          }
          acc = 0.f; cnt = 0; cur_g = g;
        }
        acc += h_d[(size_t)i * HID + lane];
        cnt++;
      }
      if (cur_g >= 0) {
        atomicAdd(&pooled_res[cur_g * HID + lane], acc);
        if (lane == 0) atomicAdd(&gcnt_res[cur_g], cnt);
      }
      if (tid < 2) pg[b * 2 + tid] = -1;
    } else {
      // common path: branchless two-bucket accumulation
      float acc_lo = 0.f, acc_hi = 0.f;
      int c_lo = 0, c_hi = 0;
      for (int i = n0 + wv; i < n1; i += 4) {
        int g = graph_id[i];
        float v = h_d[(size_t)i * HID + lane];
        bool hi = (g != g_lo);
        acc_hi += hi ? v : 0.f;
        acc_lo += hi ? 0.f : v;
        c_hi += hi ? 1 : 0;
        c_lo += hi ? 0 : 1;
      }
      ls[0][wv][lane] = acc_lo;
      ls[1][wv][lane] = acc_hi;
      if (lane == 0) { lc[0][wv] = c_lo; lc[1][wv] = c_hi; }
      __syncthreads();
      if (wv < 2) {
        float s = ls[wv][0][lane] + ls[wv][1][lane] + ls[wv][2][lane] + ls[wv][3][lane];
        part[((size_t)b * 2 + wv) * HID + lane] = s;
        if (lane == 0) {
          int cnt = lc[wv][0] + lc[wv][1] + lc[wv][2] + lc[wv][3];
          int gg = (wv == 0) ? g_lo : g_hi;
          if (wv == 1 && (g_hi == g_lo || cnt == 0)) gg = -1;
          pg[b * 2 + wv] = gg;
          pc[b * 2 + wv] = cnt;
        }
      }
    }
  }
  grid.sync();

  // ---- phase 2: k6 final (blocks 0..N_GRAPHS-1) ----
  if (blockIdx.x < N_GRAPHS) {
    const int g = blockIdx.x;
    for (int i = tid; i < NSEG; i += 256) { spg[i] = pg[i]; spc[i] = pc[i]; }
    __syncthreads();

    float acc = 0.f; int cnt = 0;
    for (int s = wv; s < NSEG; s += 4) {
      if (spg[s] == g) {
        acc += part[(size_t)s * HID + lane];
        cnt += spc[s];
      }
    }
    red[wv][lane] = acc;
    if (lane == 0) rc[wv] = cnt;
    __syncthreads();

    if (wv == 0) {
      float s = red[0][lane] + red[1][lane] + red[2][lane] + red[3][lane]
              + pooled_res[g * HID + lane];
      int c = rc[0] + rc[1] + rc[2] + rc[3] + gcnt_res[g];
      cat[lane] = s / (float)(c > 0 ? c : 1);
    }
    if (wv == 1) {
      float s = lin1_b[lane];
      const float* zr = z + g * OUT_F;
      const float* wr = lin1_w + lane * OUT_F;
      for (int k = 0; k < OUT_F; k += 4) {
        float4 zv = *(const float4*)(zr + k);
        float4 wv4 = *(const float4*)(wr + k);
        s = fmaf(zv.x, wv4.x, fmaf(zv.y, wv4.y, fmaf(zv.z, wv4.z, fmaf(zv.w, wv4.w, s))));
      }
      cat[HID + lane] = s;
    }
    __syncthreads();
    if (wv == 0) {
      float s = cat[lane] * lin2_w[lane] + cat[HID + lane] * lin2_w[HID + lane];
#pragma unroll
      for (int off = 32; off; off >>= 1) s += __shfl_xor(s, off, 64);
      if (lane == 0) out[g] = 1.f / (1.f + __expf(-(s + lin2_b[0])));
    }
  }
}

extern "C" void kernel_launch(void* const* d_in, const int* in_sizes, int n_in,
                              void* d_out, int out_size, void* d_ws, size_t ws_size,
                              hipStream_t stream) {
  (void)in_sizes; (void)n_in; (void)out_size; (void)ws_size;
  const float* h      = (const float*)d_in[0];
  const float* z      = (const float*)d_in[1];
  const int*   src    = (const int*)d_in[2];
  const int*   dst    = (const int*)d_in[3];
  const int*   gid    = (const int*)d_in[4];
  const float* fc_w   = (const float*)d_in[5];
  const float* attn_l = (const float*)d_in[6];
  const float* attn_r = (const float*)d_in[7];
  const float* bias   = (const float*)d_in[8];
  const float* lin1_w = (const float*)d_in[9];
  const float* lin1_b = (const float*)d_in[10];
  const float* lin2_w = (const float*)d_in[11];
  const float* lin2_b = (const float*)d_in[12];
  float* out = (float*)d_out;

  // workspace layout (~37 MB fp8)
  int2* pairs       = (int2*)d_ws;                              // E int2 (6.4 MB), bucket-sorted
  unsigned char* feat = (unsigned char*)(pairs + N_EDGES);      // N*ROWB bytes (9.6 MB fp8)
  float* h_d        = (float*)(feat + (size_t)N_NODES * ROWB);  // N*64 fp32
  float* el         = h_d + (size_t)N_NODES * HID;              // N*4
  float* er         = el + (size_t)N_NODES * 4;                 // N*4
  float* part       = er + (size_t)N_NODES * 4;                 // NSEG*64 (~200 KB)
  int* pg           = (int*)(part + (size_t)NSEG * HID);        // NSEG
  int* pc           = pg + NSEG;                                // NSEG
  ushort* fcb       = (ushort*)(pc + NSEG);                     // 192*128 bf16 (48 KB)
  // --- zeroed region (by kprep, uint4-wide): pooled_res, gcnt_res ---
  float* pooled_res = (float*)(fcb + 192 * NODE_F);             // 16*64
  int* gcnt_res     = (int*)(pooled_res + N_GRAPHS * HID);      // 16
  // --- end zeroed region ---
  int* offs         = gcnt_res + N_GRAPHS;                      // N+1
  int* src_s        = offs + (N_NODES + 1);                     // E int (3.2 MB), node-sorted src
  int* cnt_g        = src_s + N_EDGES;                          // H1B*NBKT (1.25 MB)
  int* base_bm      = cnt_g + (size_t)H1B * NBKT;               // NBKT*H1B (1.25 MB)
  int* btot         = base_bm + (size_t)NBKT * H1B;             // NBKT

  kprep<<<24 + ZB, 256, 0, stream>>>(fc_w, fcb, (uint4*)pooled_res);
  k01_fused<<<H1B + GB0, 256, 0, stream>>>(h, fcb, attn_l, attn_r, dst,
                                           feat, el, er, cnt_g);
  {
    void* args[] = {(void*)&src, (void*)&dst, (void*)&cnt_g, (void*)&base_bm,
                    (void*)&btot, (void*)&pairs, (void*)&src_s, (void*)&offs};
    hipLaunchCooperativeKernel((void*)ksort_coop, dim3(NBKT), dim3(256),
                               args, 0, stream);
  }
  k4_agg<<<N_NODES / 4, 256, 0, stream>>>(offs, src_s, el, er, feat, bias, h_d);
  {
    void* args[] = {(void*)&gid, (void*)&h_d, (void*)&pooled_res, (void*)&gcnt_res,
                    (void*)&part, (void*)&pg, (void*)&pc, (void*)&z,
                    (void*)&lin1_w, (void*)&lin1_b, (void*)&lin2_w, (void*)&lin2_b,
                    (void*)&out};
    hipLaunchCooperativeKernel((void*)k56_coop, dim3(K5_NB), dim3(256),
                               args, 0, stream);
  }
}

// Round 12
// 200.519 us; speedup vs baseline: 2.2409x; 2.2409x over previous
//
#include <hip/hip_runtime.h>
#include <math.h>

#define N_NODES 50000
#define N_EDGES 800000
#define N_GRAPHS 16
#define NODE_F 128
#define HID 64
#define OUT_F 128
#define HEADS 3
#define NEG 0.2f
#define FEAT (HEADS*HID)  // 192

typedef float f32x4 __attribute__((ext_vector_type(4)));
typedef float f32x2 __attribute__((ext_vector_type(2)));
typedef short bf16x8 __attribute__((ext_vector_type(8)));

#if defined(__has_builtin)
#if __has_builtin(__builtin_amdgcn_cvt_pk_f32_fp8) && __has_builtin(__builtin_amdgcn_cvt_pk_fp8_f32)
#define USE_FP8 1
#endif
#endif
#ifndef USE_FP8
#define USE_FP8 0
#endif

#if USE_FP8
#define FB 1  // bytes per stored feat element
#else
#define FB 2
#endif
// feat layout: [node][32 pair-groups][8*FB bytes]; group p = dims (2p,2p+1) x 3 heads (6*FB used)
#define GRP (8 * FB)
#define ROW (32 * GRP)

// ---- R3: atomic-free CSR build via bucket counting sort (R0-R2: global atomics ~13 G/s wall).
// ---- R4: chain compression (hist fused into GEMM, k3 fused into k4, kh2b inline).
// ---- R5 (REVERTED): mega-fusion cut waves 50k->6k; latency-bound k4 lost TLP (70us).
// ---- R6 (NULL): 4-deep gather unroll -> k4 gathers already pipelined.
// ---- R7: k01 GEMM epilogue LDS-assembled + coalesced write-out. BEST MEASURED: 201.7us.
// ---- R8/R9 (REVERTED): k5a->k4 fusion + 3-level reduce = net +12us vs R7.
// ---- R10 (NULL): packed 192B rows -> k4 gather latency-floor-bound, not traffic-bound.
// ---- R11 (REVERTED): cooperative-kernel consolidation; grid.sync ~90us on gfx950 >> gaps.
// ---- R12: revert to R7 verbatim (best measured). All structural levers probed to
//      null/regression; remaining = 44us fill tax + gather latency floor + gaps.
#define NBKT ((N_NODES + 63) / 64)   // 782
#define H1B 400                      // hist/scatter blocks
#define EPB (N_EDGES / H1B)          // 2000 edges per block (exact)
#define LROW 272                     // LDS feat row stride (17x16B; 64*272 = 17408 = sizeof A)

__device__ __forceinline__ ushort f2bf(float x) {
  union { float f; unsigned u; } v; v.f = x;
  unsigned r = v.u + 0x7fff + ((v.u >> 16) & 1);  // round-to-nearest-even
  return (ushort)(r >> 16);
}
__device__ __forceinline__ float bf2f(ushort x) {
  union { unsigned u; float f; } v; v.u = ((unsigned)x) << 16;
  return v.f;
}

// store one feat element: head hh, dim dd (bf16 fallback path only)
__device__ __forceinline__ void feat_store(unsigned char* base, int n, int hh, int dd, float v) {
  size_t off = (size_t)n * ROW + (dd >> 1) * GRP + ((hh * 2 + (dd & 1)) * FB);
#if USE_FP8
  base[off] = (unsigned char)(__builtin_amdgcn_cvt_pk_fp8_f32(v, 0.f, 0, false) & 0xff);
#else
  *(ushort*)(base + off) = f2bf(v);
#endif
}

// ---------------- KPREP: [0..23] fc_w -> fcb bf16 fragment repack | [24..25] zero residues ----------------
#define ZERO_INTS (N_GRAPHS * HID + N_GRAPHS)  // pooled_res, gcnt_res
#define ZERO_U4 (ZERO_INTS / 4)                // 260
#define ZB ((ZERO_U4 + 255) / 256)             // 2
__global__ void kprep(const float* __restrict__ fc_w, ushort* __restrict__ fcb,
                      uint4* __restrict__ zbase) {
  if (blockIdx.x >= 24) {
    int i = (blockIdx.x - 24) * 256 + threadIdx.x;
    if (i < ZERO_U4) zbase[i] = make_uint4(0, 0, 0, 0);
    return;
  }
  int i = blockIdx.x * 256 + threadIdx.x;  // [0, 6144)
  int col = i >> 5;             // [0,192)
  int kb = (i & 31) * 4;        // k base, multiple of 4
  float4 v = *(const float4*)(fc_w + (size_t)col * NODE_F + kb);
  int t = col >> 4, m = col & 15;
  int kk = kb >> 5, kq = (kb >> 3) & 3, j = kb & 7;
  size_t idx0 = ((((size_t)t * 4 + kk) * 4 + kq) * 16 + m) * 8 + j;
  ushort4 o; o.x = f2bf(v.x); o.y = f2bf(v.y); o.z = f2bf(v.z); o.w = f2bf(v.w);
  *(ushort4*)(fcb + idx0) = o;  // 8-B aligned (j in {0,4})
}

// ---------------- K01 fused: [blocks < H1B] coarse hist (LDS atomics) | [rest] MFMA GEMM ----------------
#define GB0 ((N_NODES + 63) / 64)  // 782
__global__ __launch_bounds__(256) void k01_fused(
    const float* __restrict__ h, const ushort* __restrict__ fcb,
    const float* __restrict__ attn_l, const float* __restrict__ attn_r,
    const int* __restrict__ dst,
    unsigned char* __restrict__ feat, float* __restrict__ el, float* __restrict__ er,
    int* __restrict__ cnt_g)
{
  __shared__ ushort A[64][136];   // 17408 B; hist: int cnt[NBKT]; epilogue: 64 x LROW feat rows
  const int tid = threadIdx.x;

  if (blockIdx.x < H1B) {
    int* cnt = (int*)&A[0][0];
    const int blk = blockIdx.x;
    for (int i = tid; i < NBKT; i += 256) cnt[i] = 0;
    __syncthreads();
    const int e0 = blk * EPB;
    for (int i = tid; i < EPB; i += 256)
      atomicAdd(&cnt[dst[e0 + i] >> 6], 1);
    __syncthreads();
    for (int i = tid; i < NBKT; i += 256) cnt_g[(size_t)blk * NBKT + i] = cnt[i];
    return;
  }

  const int n0 = (blockIdx.x - H1B) * 64;
  for (int i = tid; i < 64 * 32; i += 256) {
    int r = i >> 5, c4 = i & 31;
    if (n0 + r < N_NODES) {
      float4 v = *(const float4*)(h + (size_t)(n0 + r) * NODE_F + c4 * 4);
      unsigned lo = f2bf(v.x) | ((unsigned)f2bf(v.y) << 16);
      unsigned hi = f2bf(v.z) | ((unsigned)f2bf(v.w) << 16);
      *(uint2*)&A[r][c4 * 4] = make_uint2(lo, hi);
    }
  }
  __syncthreads();  // staging visible

  const int lane = tid & 63, wv = tid >> 6;
  const int m = lane & 15, kq = lane >> 4;

  f32x4 acc[12];
#pragma unroll
  for (int t = 0; t < 12; t++) acc[t] = (f32x4){0.f, 0.f, 0.f, 0.f};

#pragma unroll
  for (int kk = 0; kk < 4; kk++) {
    bf16x8 af = *(const bf16x8*)&A[wv * 16 + m][kk * 32 + kq * 8];
#pragma unroll
    for (int t = 0; t < 12; t++) {
      const bf16x8 bf = *(const bf16x8*)(fcb + ((((size_t)t * 4 + kk) * 4 + kq) * 16 + m) * 8);
      acc[t] = __builtin_amdgcn_mfma_f32_16x16x32_bf16(af, bf, acc[t], 0, 0, 0);
    }
  }

  const int rbase = n0 + wv * 16 + kq * 4;

#if USE_FP8
  // ---- R7 epilogue: LDS-assemble fp8 rows (A reused), then coalesced write-out ----
  __syncthreads();  // all waves done reading A
  unsigned char* lf = (unsigned char*)&A[0][0];  // 64 rows x LROW bytes
  const int rloc = wv * 16 + kq * 4;
#pragma unroll
  for (int t = 0; t < 12; t++) {
    const int hh = t >> 2;
    const int dd = (t & 3) * 16 + m;
    const int boff = (dd >> 1) * GRP + (hh * 2 + (dd & 1));
#pragma unroll
    for (int reg = 0; reg < 4; reg++) {
      unsigned char q = (unsigned char)(__builtin_amdgcn_cvt_pk_fp8_f32(acc[t][reg], 0.f, 0, false) & 0xff);
      lf[(rloc + reg) * LROW + boff] = q;
    }
  }
#else
#pragma unroll
  for (int t = 0; t < 12; t++) {
    const int hh = t >> 2;
    const int dd = (t & 3) * 16 + m;
#pragma unroll
    for (int reg = 0; reg < 4; reg++) {
      int n = rbase + reg;
      if (n < N_NODES) feat_store(feat, n, hh, dd, acc[t][reg]);
    }
  }
#endif

  // el/er epilogue (registers + shfl only) — overlaps the LDS scatter latency
#pragma unroll
  for (int hh = 0; hh < HEADS; hh++) {
    float elv[4] = {0.f, 0.f, 0.f, 0.f};
    float erv[4] = {0.f, 0.f, 0.f, 0.f};
#pragma unroll
    for (int tt = 0; tt < 4; tt++) {
      int t = hh * 4 + tt;
      float al = attn_l[hh * HID + tt * 16 + m];
      float ar = attn_r[hh * HID + tt * 16 + m];
#pragma unroll
      for (int reg = 0; reg < 4; reg++) {
        elv[reg] = fmaf(acc[t][reg], al, elv[reg]);
        erv[reg] = fmaf(acc[t][reg], ar, erv[reg]);
      }
    }
#pragma unroll
    for (int reg = 0; reg < 4; reg++) {
#pragma unroll
      for (int off = 1; off < 16; off <<= 1) {
        elv[reg] += __shfl_xor(elv[reg], off, 64);
        erv[reg] += __shfl_xor(erv[reg], off, 64);
      }
      int n = rbase + reg;
      if (m == 0 && n < N_NODES) {
        el[(size_t)n * 4 + hh] = elv[reg];
        er[(size_t)n * 4 + hh] = erv[reg];
      }
    }
  }

#if USE_FP8
  __syncthreads();  // LDS rows complete
  // coalesced write-out: 64 rows x 256 B; 4 x dwordx4 per thread
  for (int i = tid; i < 64 * (ROW / 16); i += 256) {
    int r = i >> 4, c = (i & 15) * 16;
    int n = n0 + r;
    if (n < N_NODES)
      *(uint4*)(feat + (size_t)n * ROW + c) = *(const uint4*)(lf + r * LROW + c);
  }
#endif
}

// ---------------- KH2a: per-bucket exclusive scan over blocks (1 wave / bucket) ----------------
#define H2A_K 7  // ceil(400/64)
__global__ __launch_bounds__(64) void kh2a_scan(
    const int* __restrict__ cnt_g, int* __restrict__ base_bm, int* __restrict__ btot)
{
  const int b = blockIdx.x;       // bucket
  const int lane = threadIdx.x;   // 0..63
  int v[H2A_K];
  int lt = 0;
#pragma unroll
  for (int j = 0; j < H2A_K; j++) {
    int g = lane * H2A_K + j;
    v[j] = (g < H1B) ? cnt_g[(size_t)g * NBKT + b] : 0;
    lt += v[j];
  }
  int s = lt;
#pragma unroll
  for (int off = 1; off < 64; off <<= 1) {
    int t = __shfl_up(s, off, 64);
    if (lane >= off) s += t;
  }
  int excl = s - lt;  // exclusive prefix of this lane's chunk
#pragma unroll
  for (int j = 0; j < H2A_K; j++) {
    int g = lane * H2A_K + j;
    if (g < H1B) base_bm[(size_t)b * H1B + g] = excl;
    excl += v[j];
  }
  if (lane == 63) btot[b] = s;  // bucket total
}

// ---------------- KH3: scatter (src,dst) into bucket-sorted order via LDS cursors ----------------
__global__ __launch_bounds__(256) void kh3_scatter(
    const int* __restrict__ src, const int* __restrict__ dst,
    const int* __restrict__ btot, const int* __restrict__ base_bm,
    int2* __restrict__ pairs)
{
  __shared__ int cur[NBKT];
  __shared__ int wsum[4];
  const int tid = threadIdx.x, blk = blockIdx.x;
  const int lane = tid & 63, wv = tid >> 6;
  // per-thread 4-slot chunk scan of btot
  int v[4]; int lt = 0;
#pragma unroll
  for (int j = 0; j < 4; j++) {
    int g = tid * 4 + j;
    v[j] = (g < NBKT) ? btot[g] : 0;
    lt += v[j];
  }
  int s = lt;
#pragma unroll
  for (int off = 1; off < 64; off <<= 1) {
    int t = __shfl_up(s, off, 64);
    if (lane >= off) s += t;
  }
  if (lane == 63) wsum[wv] = s;
  __syncthreads();
  int woff = 0;
#pragma unroll
  for (int w = 0; w < 4; w++) woff += (w < wv) ? wsum[w] : 0;
  int excl = s - lt + woff;  // exclusive prefix over btot[0 .. tid*4-1]
#pragma unroll
  for (int j = 0; j < 4; j++) {
    int g = tid * 4 + j;
    if (g < NBKT) cur[g] = excl + base_bm[(size_t)g * H1B + blk];
    excl += v[j];
  }
  __syncthreads();
  const int e0 = blk * EPB;
  for (int i = tid; i < EPB; i += 256) {
    int e = e0 + i;
    int d = dst[e], sv = src[e];
    int slot = atomicAdd(&cur[d >> 6], 1);  // returning LDS atomic (fast pipe)
    pairs[slot] = make_int2(sv, d);
  }
}

// ---------------- KH4: per-bucket node sort -> exact CSR offs + node-sorted src ----------------
__global__ __launch_bounds__(256) void kh4_nodesort(
    const int2* __restrict__ pairs, const int* __restrict__ btot,
    int* __restrict__ src_s, int* __restrict__ offs)
{
  __shared__ int nodecnt[64];
  __shared__ int cur[64];
  __shared__ int red_[4];
  __shared__ int lo_s, hi_s;
  const int b = blockIdx.x, tid = threadIdx.x;
  const int lane = tid & 63, wv = tid >> 6;
  // inline prefix: lo = sum(btot[0..b-1])
  int partial = 0;
  for (int i = tid; i < b; i += 256) partial += btot[i];
#pragma unroll
  for (int off = 32; off; off >>= 1) partial += __shfl_xor(partial, off, 64);
  if (lane == 0) red_[wv] = partial;
  if (tid < 64) nodecnt[tid] = 0;
  __syncthreads();
  if (tid == 0) {
    int l = red_[0] + red_[1] + red_[2] + red_[3];
    lo_s = l; hi_s = l + btot[b];
  }
  __syncthreads();
  const int lo = lo_s, hi = hi_s;
  for (int i = lo + tid; i < hi; i += 256)
    atomicAdd(&nodecnt[pairs[i].y & 63], 1);
  __syncthreads();
  if (tid < 64) {
    int v = nodecnt[tid];
    int s = v;
#pragma unroll
    for (int off = 1; off < 64; off <<= 1) {
      int t = __shfl_up(s, off, 64);
      if (tid >= off) s += t;
    }
    int excl = s - v;
    cur[tid] = lo + excl;
    int n = b * 64 + tid;
    if (n < N_NODES) offs[n] = lo + excl;
    if (b == NBKT - 1 && tid == 0) offs[N_NODES] = N_EDGES;  // sentinel
  }
  __syncthreads();
  for (int i = lo + tid; i < hi; i += 256) {
    int2 pr = pairs[i];
    int slot = atomicAdd(&cur[pr.y & 63], 1);
    src_s[slot] = pr.x;  // only src needed downstream (dst == node of CSR row)
  }
}

// ---------------- K4: wave per node; weights inline ----------------
__global__ __launch_bounds__(256) void k4_agg(
    const int* __restrict__ offs, const int* __restrict__ src_s,
    const float* __restrict__ el4, const float* __restrict__ er4,
    const unsigned char* __restrict__ feat, const float* __restrict__ bias,
    float* __restrict__ h_d)
{
  __shared__ float4 rec[4][64];  // per-wave staging, 4 KB/block
  const int wv = threadIdx.x >> 6, lane = threadIdx.x & 63;
  const int n = blockIdx.x * 4 + wv;  // grid exact: N/4
  const int lo = offs[n], hi = offs[n + 1];
  const int half = lane >> 5;
  const int d = lane & 31;
  const char* fb = (const char*)feat;
  const float4 ern = ((const float4*)er4)[n];

  float a0x = 0.f, a0y = 0.f, a1x = 0.f, a1y = 0.f, a2x = 0.f, a2y = 0.f;
  float s0 = 0.f, s1 = 0.f, s2 = 0.f;

  for (int base = lo; base < hi; base += 64) {
    const int cnt = min(64, hi - base);
    if (lane < cnt) {
      int sidx = src_s[base + lane];
      float4 elv = ((const float4*)el4)[sidx];
      float e0 = elv.x + ern.x; e0 = e0 > 0.f ? e0 : NEG * e0;
      float e1 = elv.y + ern.y; e1 = e1 > 0.f ? e1 : NEG * e1;
      float e2 = elv.z + ern.z; e2 = e2 > 0.f ? e2 : NEG * e2;
      float4 c;
      c.x = __expf(e0); c.y = __expf(e1); c.z = __expf(e2);
      c.w = __int_as_float(sidx * ROW);  // byte offset of feat row
      rec[wv][lane] = c;
      s0 += c.x; s1 += c.y; s2 += c.z;  // each edge counted once (by its staging lane)
    }
#define K4_BODY(J) do { \
      float4 c = rec[wv][J]; \
      const char* rp = fb + __float_as_int(c.w) + GRP * d; \
      f32x2 f0, f1, f2; \
      if (USE_FP8) { \
        uint2 q = *(const uint2*)rp; \
        f0 = __builtin_amdgcn_cvt_pk_f32_fp8(q.x & 0xffff, false); \
        f1 = __builtin_amdgcn_cvt_pk_f32_fp8(q.x >> 16, false); \
        f2 = __builtin_amdgcn_cvt_pk_f32_fp8(q.y & 0xffff, false); \
      } else { \
        uint4 q = *(const uint4*)rp; \
        f0.x = bf2f((ushort)(q.x & 0xffff)); f0.y = bf2f((ushort)(q.x >> 16)); \
        f1.x = bf2f((ushort)(q.y & 0xffff)); f1.y = bf2f((ushort)(q.y >> 16)); \
        f2.x = bf2f((ushort)(q.z & 0xffff)); f2.y = bf2f((ushort)(q.z >> 16)); \
      } \
      a0x = fmaf(c.x, f0.x, a0x); a0y = fmaf(c.x, f0.y, a0y); \
      a1x = fmaf(c.y, f1.x, a1x); a1y = fmaf(c.y, f1.y, a1y); \
      a2x = fmaf(c.z, f2.x, a2x); a2y = fmaf(c.z, f2.y, a2y); \
    } while (0)
    int j = half;
    for (; j + 2 < cnt; j += 4) { K4_BODY(j); K4_BODY(j + 2); }
    if (j < cnt) K4_BODY(j);
#undef K4_BODY
  }
  // combine the two half-wave edge partitions (same dims, disjoint edges)
  a0x += __shfl_xor(a0x, 32, 64); a0y += __shfl_xor(a0y, 32, 64);
  a1x += __shfl_xor(a1x, 32, 64); a1y += __shfl_xor(a1y, 32, 64);
  a2x += __shfl_xor(a2x, 32, 64); a2y += __shfl_xor(a2y, 32, 64);
#pragma unroll
  for (int off = 32; off; off >>= 1) {
    s0 += __shfl_xor(s0, off, 64);
    s1 += __shfl_xor(s1, off, 64);
    s2 += __shfl_xor(s2, off, 64);
  }
  const float i0 = s0 > 0.f ? 1.f / s0 : 0.f;
  const float i1 = s1 > 0.f ? 1.f / s1 : 0.f;
  const float i2 = s2 > 0.f ? 1.f / s2 : 0.f;
  if (half == 0) {
    float2 b0 = *(const float2*)(bias + 2 * d);
    float2 b1 = *(const float2*)(bias + HID + 2 * d);
    float2 b2 = *(const float2*)(bias + 2 * HID + 2 * d);
    float2 o;
    o.x = (fmaf(a0x, i0, b0.x) + fmaf(a1x, i1, b1.x) + fmaf(a2x, i2, b2.x)) * (1.f / 3.f);
    o.y = (fmaf(a0y, i0, b0.y) + fmaf(a1y, i1, b1.y) + fmaf(a2y, i2, b2.y)) * (1.f / 3.f);
    *(float2*)(h_d + (size_t)n * HID + 2 * d) = o;
  }
}

// ---------------- K5a: atomic-free block partials (sorted graph_id, span<=2 fast path) ----------------
#define K5_NPB 128
#define K5_NB ((N_NODES + K5_NPB - 1) / K5_NPB)  // 391
#define NSEG (K5_NB * 2)                         // 782
__global__ __launch_bounds__(256) void k5a_partial(
    const int* __restrict__ graph_id, const float* __restrict__ h_d,
    float* __restrict__ pooled_res, int* __restrict__ gcnt_res,  // rare-path residue
    float* __restrict__ part, int* __restrict__ pg, int* __restrict__ pc)
{
  const int wv = threadIdx.x >> 6, lane = threadIdx.x & 63;
  const int b = blockIdx.x;
  const int n0 = b * K5_NPB;
  const int n1 = min(n0 + K5_NPB, N_NODES);
  const int g_lo = graph_id[n0], g_hi = graph_id[n1 - 1];

  if (g_hi > g_lo + 1) {
    // rare path (a graph smaller than the block span): per-wave atomic flush
    float acc = 0.f; int cur_g = -1; int cnt = 0;
    for (int i = n0 + wv; i < n1; i += 4) {
      int g = graph_id[i];
      if (g != cur_g) {
        if (cur_g >= 0) {
          atomicAdd(&pooled_res[cur_g * HID + lane], acc);
          if (lane == 0) atomicAdd(&gcnt_res[cur_g], cnt);
        }
        acc = 0.f; cnt = 0; cur_g = g;
      }
      acc += h_d[(size_t)i * HID + lane];
      cnt++;
    }
    if (cur_g >= 0) {
      atomicAdd(&pooled_res[cur_g * HID + lane], acc);
      if (lane == 0) atomicAdd(&gcnt_res[cur_g], cnt);
    }
    if (threadIdx.x < 2) pg[b * 2 + threadIdx.x] = -1;
    return;
  }

  // common path: branchless two-bucket accumulation, no atomics, no fences
  float acc_lo = 0.f, acc_hi = 0.f;
  int c_lo = 0, c_hi = 0;
  for (int i = n0 + wv; i < n1; i += 4) {
    int g = graph_id[i];
    float v = h_d[(size_t)i * HID + lane];
    bool hi = (g != g_lo);
    acc_hi += hi ? v : 0.f;
    acc_lo += hi ? 0.f : v;
    c_hi += hi ? 1 : 0;
    c_lo += hi ? 0 : 1;
  }
  __shared__ float ls[2][4][64];
  __shared__ int lc[2][4];
  ls[0][wv][lane] = acc_lo;
  ls[1][wv][lane] = acc_hi;
  if (lane == 0) { lc[0][wv] = c_lo; lc[1][wv] = c_hi; }
  __syncthreads();
  if (wv < 2) {
    float s = ls[wv][0][lane] + ls[wv][1][lane] + ls[wv][2][lane] + ls[wv][3][lane];
    part[((size_t)b * 2 + wv) * HID + lane] = s;
    if (lane == 0) {
      int cnt = lc[wv][0] + lc[wv][1] + lc[wv][2] + lc[wv][3];
      int gg = (wv == 0) ? g_lo : g_hi;
      if (wv == 1 && (g_hi == g_lo || cnt == 0)) gg = -1;
      pg[b * 2 + wv] = gg;
      pc[b * 2 + wv] = cnt;
    }
  }
}

// ---------------- K6: 16 blocks (one per graph) — reduce own segments + per-graph MLP ----------------
__global__ __launch_bounds__(256) void k6_final(
    const float* __restrict__ part, const int* __restrict__ pg, const int* __restrict__ pc,
    const float* __restrict__ pooled_res, const int* __restrict__ gcnt_res,
    const float* __restrict__ z,
    const float* __restrict__ lin1_w, const float* __restrict__ lin1_b,
    const float* __restrict__ lin2_w, const float* __restrict__ lin2_b,
    float* __restrict__ out)
{
  const int g = blockIdx.x;
  const int tid = threadIdx.x, wv = tid >> 6, lane = tid & 63;
  __shared__ int spg[NSEG], spc[NSEG];
  __shared__ float red[4][HID];
  __shared__ int rc[4];
  __shared__ float cat[2 * HID];

  for (int i = tid; i < NSEG; i += 256) { spg[i] = pg[i]; spc[i] = pc[i]; }
  __syncthreads();

  float acc = 0.f; int cnt = 0;
  for (int s = wv; s < NSEG; s += 4) {
    if (spg[s] == g) {
      acc += part[(size_t)s * HID + lane];
      cnt += spc[s];
    }
  }
  red[wv][lane] = acc;
  if (lane == 0) rc[wv] = cnt;
  __syncthreads();

  if (wv == 0) {
    float s = red[0][lane] + red[1][lane] + red[2][lane] + red[3][lane]
            + pooled_res[g * HID + lane];
    int c = rc[0] + rc[1] + rc[2] + rc[3] + gcnt_res[g];
    cat[lane] = s / (float)(c > 0 ? c : 1);
  }
  if (wv == 1) {
    float s = lin1_b[lane];
    const float* zr = z + g * OUT_F;
    const float* wr = lin1_w + lane * OUT_F;
    for (int k = 0; k < OUT_F; k += 4) {
      float4 zv = *(const float4*)(zr + k);
      float4 wv4 = *(const float4*)(wr + k);
      s = fmaf(zv.x, wv4.x, fmaf(zv.y, wv4.y, fmaf(zv.z, wv4.z, fmaf(zv.w, wv4.w, s))));
    }
    cat[HID + lane] = s;
  }
  __syncthreads();
  if (wv == 0) {
    float s = cat[lane] * lin2_w[lane] + cat[HID + lane] * lin2_w[HID + lane];
#pragma unroll
    for (int off = 32; off; off >>= 1) s += __shfl_xor(s, off, 64);
    if (lane == 0) out[g] = 1.f / (1.f + __expf(-(s + lin2_b[0])));
  }
}

extern "C" void kernel_launch(void* const* d_in, const int* in_sizes, int n_in,
                              void* d_out, int out_size, void* d_ws, size_t ws_size,
                              hipStream_t stream) {
  (void)in_sizes; (void)n_in; (void)out_size; (void)ws_size;
  const float* h      = (const float*)d_in[0];
  const float* z      = (const float*)d_in[1];
  const int*   src    = (const int*)d_in[2];
  const int*   dst    = (const int*)d_in[3];
  const int*   gid    = (const int*)d_in[4];
  const float* fc_w   = (const float*)d_in[5];
  const float* attn_l = (const float*)d_in[6];
  const float* attn_r = (const float*)d_in[7];
  const float* bias   = (const float*)d_in[8];
  const float* lin1_w = (const float*)d_in[9];
  const float* lin1_b = (const float*)d_in[10];
  const float* lin2_w = (const float*)d_in[11];
  const float* lin2_b = (const float*)d_in[12];
  float* out = (float*)d_out;

  // workspace layout (~40 MB fp8)
  int2* pairs       = (int2*)d_ws;                              // E int2 (6.4 MB), bucket-sorted
  unsigned char* feat = (unsigned char*)(pairs + N_EDGES);      // N*ROW bytes
  float* h_d        = (float*)(feat + (size_t)N_NODES * ROW);   // N*64 fp32
  float* el         = h_d + (size_t)N_NODES * HID;              // N*4
  float* er         = el + (size_t)N_NODES * 4;                 // N*4
  float* part       = er + (size_t)N_NODES * 4;                 // NSEG*64 (~200 KB)
  int* pg           = (int*)(part + (size_t)NSEG * HID);        // NSEG
  int* pc           = pg + NSEG;                                // NSEG
  ushort* fcb       = (ushort*)(pc + NSEG);                     // 192*128 bf16 (48 KB)
  // --- zeroed region (by kprep, uint4-wide): pooled_res, gcnt_res ---
  float* pooled_res = (float*)(fcb + 192 * NODE_F);             // 16*64
  int* gcnt_res     = (int*)(pooled_res + N_GRAPHS * HID);      // 16
  // --- end zeroed region ---
  int* offs         = gcnt_res + N_GRAPHS;                      // N+1
  int* src_s        = offs + (N_NODES + 1);                     // E int (3.2 MB), node-sorted src
  int* cnt_g        = src_s + N_EDGES;                          // H1B*NBKT (1.25 MB)
  int* base_bm      = cnt_g + (size_t)H1B * NBKT;               // NBKT*H1B (1.25 MB)
  int* btot         = base_bm + (size_t)NBKT * H1B;             // NBKT

  kprep<<<24 + ZB, 256, 0, stream>>>(fc_w, fcb, (uint4*)pooled_res);
  k01_fused<<<H1B + GB0, 256, 0, stream>>>(h, fcb, attn_l, attn_r, dst,
                                           feat, el, er, cnt_g);
  kh2a_scan<<<NBKT, 64, 0, stream>>>(cnt_g, base_bm, btot);
  kh3_scatter<<<H1B, 256, 0, stream>>>(src, dst, btot, base_bm, pairs);
  kh4_nodesort<<<NBKT, 256, 0, stream>>>(pairs, btot, src_s, offs);
  k4_agg<<<N_NODES / 4, 256, 0, stream>>>(offs, src_s, el, er, feat, bias, h_d);
  k5a_partial<<<K5_NB, 256, 0, stream>>>(gid, h_d, pooled_res, gcnt_res, part, pg, pc);
  k6_final<<<N_GRAPHS, 256, 0, stream>>>(part, pg, pc, pooled_res, gcnt_res,
                                         z, lin1_w, lin1_b, lin2_w, lin2_b, out);
}